// Round 3
// baseline (476.228 us; speedup 1.0000x reference)
//
#include <hip/hip_runtime.h>
#include <hip/hip_cooperative_groups.h>
#include <stdint.h>

namespace cg = cooperative_groups;

#define HH 2048
#define WW 2048
#define HW (HH * WW)

// ws layout (uint32 index):
// [0] minbits, [1] maxbits, [2..257] hist, [258..513] cdf (float), [514..519] acc (float)
// acc: 0=recon_low, 1=recon_eq, 2=sum|dRg|, 3=sumRg, 4=sum|dL|e^-10|dRg|, 5=sum L*e^-10Rg

__device__ __forceinline__ float gray_pil(float r, float g, float b) {
    float qr = floorf(fminf(fmaxf(r, 0.f), 1.f) * 255.f);
    float qg = floorf(fminf(fmaxf(g, 0.f), 1.f) * 255.f);
    float qb = floorf(fminf(fmaxf(b, 0.f), 1.f) * 255.f);
    // all terms integers < 2^24: exact in fp32
    float s = floorf((qr * 19595.f + qg * 38470.f + qb * 7471.f + 32768.f) * (1.f / 65536.f));
    return s * (1.f / 255.f);
}

struct Row { float4 r0, r1, r2, i0, i1, i2, lv; };

__device__ __forceinline__ Row load_row(const float* __restrict__ im,
                                        const float* __restrict__ R,
                                        const float* __restrict__ L, int p) {
    Row q;
    q.r0 = *(const float4*)(R + p);
    q.r1 = *(const float4*)(R + p + HW);
    q.r2 = *(const float4*)(R + p + 2 * HW);
    q.i0 = *(const float4*)(im + p);
    q.i1 = *(const float4*)(im + p + HW);
    q.i2 = *(const float4*)(im + p + 2 * HW);
    q.lv = *(const float4*)(L + p);
    return q;
}

__device__ __forceinline__ void px(float r0, float r1, float r2,
                                   float i0, float i1, float i2, float l,
                                   float& rgp, float& lp,
                                   const float* __restrict__ scdf, float gmin, float inv_dw,
                                   float& a0, float& a1, float& a2,
                                   float& a3, float& a4, float& a5) {
    a0 += fabsf(r0 * l - i0) + fabsf(r1 * l - i1) + fabsf(r2 * l - i2);
    float rmax = fmaxf(r0, fmaxf(r1, r2));
    float imax = fmaxf(i0, fmaxf(i1, i2));
    float t = (imax - gmin) * inv_dw;
    int bi = (int)t;
    float eq;
    if (bi >= 255) eq = scdf[255];
    else {
        float fr = t - (float)bi;
        eq = scdf[bi] + fr * (scdf[bi + 1] - scdf[bi]);
    }
    a1 += fabsf(rmax - eq);
    float rg = gray_pil(r0, r1, r2);
    a3 += rg;
    a5 += l * __expf(-10.f * rg);
    float drg = fabsf(rg - rgp);
    a2 += drg;
    a4 += fabsf(l - lp) * __expf(-10.f * drg);
    rgp = rg;
    lp = l;
}

__device__ __forceinline__ void row_math(const Row& q, float rgp[4], float lp[4],
                                         const float* __restrict__ scdf, float gmin, float inv_dw,
                                         float& a0, float& a1, float& a2,
                                         float& a3, float& a4, float& a5) {
    px(q.r0.x, q.r1.x, q.r2.x, q.i0.x, q.i1.x, q.i2.x, q.lv.x, rgp[0], lp[0], scdf, gmin, inv_dw, a0, a1, a2, a3, a4, a5);
    px(q.r0.y, q.r1.y, q.r2.y, q.i0.y, q.i1.y, q.i2.y, q.lv.y, rgp[1], lp[1], scdf, gmin, inv_dw, a0, a1, a2, a3, a4, a5);
    px(q.r0.z, q.r1.z, q.r2.z, q.i0.z, q.i1.z, q.i2.z, q.lv.z, rgp[2], lp[2], scdf, gmin, inv_dw, a0, a1, a2, a3, a4, a5);
    px(q.r0.w, q.r1.w, q.r2.w, q.i0.w, q.i1.w, q.i2.w, q.lv.w, rgp[3], lp[3], scdf, gmin, inv_dw, a0, a1, a2, a3, a4, a5);
}

__device__ __forceinline__ void prev_row(const float* __restrict__ R,
                                         const float* __restrict__ L,
                                         int h0, int w, float rgp[4], float lp[4]) {
    if (h0 > 0) {
        int p = (h0 - 1) * WW + w;
        float4 Ra = *(const float4*)(R + p);
        float4 Rb = *(const float4*)(R + p + HW);
        float4 Rc = *(const float4*)(R + p + 2 * HW);
        float4 Lv = *(const float4*)(L + p);
        rgp[0] = gray_pil(Ra.x, Rb.x, Rc.x); lp[0] = Lv.x;
        rgp[1] = gray_pil(Ra.y, Rb.y, Rc.y); lp[1] = Lv.y;
        rgp[2] = gray_pil(Ra.z, Rb.z, Rc.z); lp[2] = Lv.z;
        rgp[3] = gray_pil(Ra.w, Rb.w, Rc.w); lp[3] = Lv.w;
    } else {
        rgp[0] = rgp[1] = rgp[2] = rgp[3] = 0.f;
        lp[0] = lp[1] = lp[2] = lp[3] = 0.f;
    }
}

__global__ __launch_bounds__(256, 4)
void mega_k(const float* __restrict__ im, const float* __restrict__ R,
            const float* __restrict__ L, uint32_t* __restrict__ ctl,
            float* __restrict__ out) {
    cg::grid_group grid = cg::this_grid();
    const int T = (int)(gridDim.x * 256u);
    const int tid = (int)(blockIdx.x * 256u + threadIdx.x);
    const int lane = threadIdx.x & 63, wv = threadIdx.x >> 6;

    __shared__ uint32_t lh[256];
    __shared__ float scdf[256];
    __shared__ float red[6][4];

    // ---- P0: init workspace ----
    if (blockIdx.x == 0) {
        ctl[2 + threadIdx.x] = 0u;
        if (threadIdx.x < 6) ((float*)ctl)[514 + threadIdx.x] = 0.f;
        if (threadIdx.x == 0) { ctl[0] = 0x7F800000u; ctl[1] = 0u; }
    }
    grid.sync();

    // ---- P1: min/max of per-pixel channel max ----
    const float4* im4 = (const float4*)im;
    const int N4 = HW / 4;
    float vmin = __uint_as_float(0x7F800000u), vmax = 0.f;
    {
        int i = tid;
        for (; i + T < N4; i += 2 * T) {
            float4 a0 = im4[i], b0 = im4[i + N4], c0 = im4[i + 2 * N4];
            float4 a1 = im4[i + T], b1 = im4[i + T + N4], c1 = im4[i + T + 2 * N4];
            float m0 = fmaxf(a0.x, fmaxf(b0.x, c0.x));
            float m1 = fmaxf(a0.y, fmaxf(b0.y, c0.y));
            float m2 = fmaxf(a0.z, fmaxf(b0.z, c0.z));
            float m3 = fmaxf(a0.w, fmaxf(b0.w, c0.w));
            float m4 = fmaxf(a1.x, fmaxf(b1.x, c1.x));
            float m5 = fmaxf(a1.y, fmaxf(b1.y, c1.y));
            float m6 = fmaxf(a1.z, fmaxf(b1.z, c1.z));
            float m7 = fmaxf(a1.w, fmaxf(b1.w, c1.w));
            vmin = fminf(vmin, fminf(fminf(fminf(m0, m1), fminf(m2, m3)),
                                     fminf(fminf(m4, m5), fminf(m6, m7))));
            vmax = fmaxf(vmax, fmaxf(fmaxf(fmaxf(m0, m1), fmaxf(m2, m3)),
                                     fmaxf(fmaxf(m4, m5), fmaxf(m6, m7))));
        }
        if (i < N4) {
            float4 a0 = im4[i], b0 = im4[i + N4], c0 = im4[i + 2 * N4];
            float m0 = fmaxf(a0.x, fmaxf(b0.x, c0.x));
            float m1 = fmaxf(a0.y, fmaxf(b0.y, c0.y));
            float m2 = fmaxf(a0.z, fmaxf(b0.z, c0.z));
            float m3 = fmaxf(a0.w, fmaxf(b0.w, c0.w));
            vmin = fminf(vmin, fminf(fminf(m0, m1), fminf(m2, m3)));
            vmax = fmaxf(vmax, fmaxf(fmaxf(m0, m1), fmaxf(m2, m3)));
        }
    }
    for (int off = 32; off; off >>= 1) {
        vmin = fminf(vmin, __shfl_down(vmin, off));
        vmax = fmaxf(vmax, __shfl_down(vmax, off));
    }
    if (lane == 0) { red[0][wv] = vmin; red[1][wv] = vmax; }
    __syncthreads();
    if (threadIdx.x == 0) {
        float m = red[0][0], M = red[1][0];
        for (int k = 1; k < 4; k++) { m = fminf(m, red[0][k]); M = fmaxf(M, red[1][k]); }
        atomicMin(&ctl[0], __float_as_uint(m));  // values >= 0: uint order == float order
        atomicMax(&ctl[1], __float_as_uint(M));
    }
    grid.sync();

    // ---- P2: 256-bin histogram ----
    float gmin = __uint_as_float(((volatile uint32_t*)ctl)[0]);
    float gmax = __uint_as_float(((volatile uint32_t*)ctl)[1]);
    float inv_dw = 256.0f / (gmax - gmin);
    lh[threadIdx.x] = 0u;
    __syncthreads();
    {
        int i = tid;
        for (; i + T < N4; i += 2 * T) {
            float4 a0 = im4[i], b0 = im4[i + N4], c0 = im4[i + 2 * N4];
            float4 a1 = im4[i + T], b1 = im4[i + T + N4], c1 = im4[i + T + 2 * N4];
            float m[8];
            m[0] = fmaxf(a0.x, fmaxf(b0.x, c0.x));
            m[1] = fmaxf(a0.y, fmaxf(b0.y, c0.y));
            m[2] = fmaxf(a0.z, fmaxf(b0.z, c0.z));
            m[3] = fmaxf(a0.w, fmaxf(b0.w, c0.w));
            m[4] = fmaxf(a1.x, fmaxf(b1.x, c1.x));
            m[5] = fmaxf(a1.y, fmaxf(b1.y, c1.y));
            m[6] = fmaxf(a1.z, fmaxf(b1.z, c1.z));
            m[7] = fmaxf(a1.w, fmaxf(b1.w, c1.w));
#pragma unroll
            for (int j = 0; j < 8; ++j) {
                int b = (int)((m[j] - gmin) * inv_dw);
                b = b < 0 ? 0 : (b > 255 ? 255 : b);
                atomicAdd(&lh[b], 1u);
            }
        }
        if (i < N4) {
            float4 a0 = im4[i], b0 = im4[i + N4], c0 = im4[i + 2 * N4];
            float m[4];
            m[0] = fmaxf(a0.x, fmaxf(b0.x, c0.x));
            m[1] = fmaxf(a0.y, fmaxf(b0.y, c0.y));
            m[2] = fmaxf(a0.z, fmaxf(b0.z, c0.z));
            m[3] = fmaxf(a0.w, fmaxf(b0.w, c0.w));
#pragma unroll
            for (int j = 0; j < 4; ++j) {
                int b = (int)((m[j] - gmin) * inv_dw);
                b = b < 0 ? 0 : (b > 255 ? 255 : b);
                atomicAdd(&lh[b], 1u);
            }
        }
    }
    __syncthreads();
    if (lh[threadIdx.x]) atomicAdd(&ctl[2 + threadIdx.x], lh[threadIdx.x]);
    grid.sync();

    // ---- P3: cdf (serial, trivial) ----
    if (tid == 0) {
        float* cdf = (float*)(ctl + 258);
        unsigned long long c = 0;
        for (int k = 0; k < 256; k++) {
            c += ((volatile uint32_t*)ctl)[2 + k];
            cdf[k] = (float)((double)c / (double)HW);
        }
    }
    grid.sync();

    // ---- P4: main fused loss pass (4 cols x 4 rows per item, 2 items in lockstep) ----
    scdf[threadIdx.x] = ((const float*)(ctl + 258))[threadIdx.x];
    __syncthreads();

    const int NIT = (WW / 4) * (HH / 4);  // 512 * 512
    float a0 = 0.f, a1 = 0.f, a2 = 0.f, a3 = 0.f, a4 = 0.f, a5 = 0.f;

    for (int base = tid; base < NIT; base += 2 * T) {
        int i1 = base + T;
        bool two = (i1 < NIT);
        int w0 = (base & 511) * 4, h00 = (base >> 9) * 4;
        int w1 = 0, h01 = 0;
        if (two) { w1 = (i1 & 511) * 4; h01 = (i1 >> 9) * 4; }

        float rgp0[4], lp0[4], rgp1[4], lp1[4];
        prev_row(R, L, h00, w0, rgp0, lp0);
        if (two) prev_row(R, L, h01, w1, rgp1, lp1);

#pragma unroll
        for (int h = 0; h < 4; ++h) {
            Row q0 = load_row(im, R, L, (h00 + h) * WW + w0);
            Row q1;
            if (two) q1 = load_row(im, R, L, (h01 + h) * WW + w1);
            row_math(q0, rgp0, lp0, scdf, gmin, inv_dw, a0, a1, a2, a3, a4, a5);
            if (two) row_math(q1, rgp1, lp1, scdf, gmin, inv_dw, a0, a1, a2, a3, a4, a5);
        }
        if (h00 + 4 == HH) {
#pragma unroll
            for (int j = 0; j < 4; ++j) {
                a2 += rgp0[j];
                a4 += lp0[j] * __expf(-10.f * rgp0[j]);
            }
        }
        if (two && h01 + 4 == HH) {
#pragma unroll
            for (int j = 0; j < 4; ++j) {
                a2 += rgp1[j];
                a4 += lp1[j] * __expf(-10.f * rgp1[j]);
            }
        }
    }

    for (int off = 32; off; off >>= 1) {
        a0 += __shfl_down(a0, off);
        a1 += __shfl_down(a1, off);
        a2 += __shfl_down(a2, off);
        a3 += __shfl_down(a3, off);
        a4 += __shfl_down(a4, off);
        a5 += __shfl_down(a5, off);
    }
    __syncthreads();  // red[] reuse from P1
    if (lane == 0) {
        red[0][wv] = a0; red[1][wv] = a1; red[2][wv] = a2;
        red[3][wv] = a3; red[4][wv] = a4; red[5][wv] = a5;
    }
    __syncthreads();
    if (threadIdx.x == 0) {
        float s0 = 0, s1 = 0, s2 = 0, s3 = 0, s4 = 0, s5 = 0;
        for (int k = 0; k < 4; k++) {
            s0 += red[0][k]; s1 += red[1][k]; s2 += red[2][k];
            s3 += red[3][k]; s4 += red[4][k]; s5 += red[5][k];
        }
        float* acc = (float*)(ctl + 514);
        atomicAdd(&acc[0], s0);
        atomicAdd(&acc[1], s1);
        atomicAdd(&acc[2], s2);
        atomicAdd(&acc[3], s3);
        atomicAdd(&acc[4], s4);
        atomicAdd(&acc[5], s5);
    }
    grid.sync();

    // ---- P5: finalize ----
    if (tid == 0) {
        const volatile float* acc = (const volatile float*)(ctl + 514);
        float recon_low = acc[0] / (3.0f * (float)HW);
        float recon_eq = acc[1] / (float)HW;
        float denom = 2.0f * 2049.0f * 2050.0f;
        float r_smooth = (acc[2] + 2.f * acc[3]) / denom;
        float ismooth = (acc[4] + 2.f * acc[5]) / denom;
        out[0] = recon_low + 0.1f * ismooth + 0.1f * recon_eq + 0.01f * r_smooth;
    }
}

extern "C" void kernel_launch(void* const* d_in, const int* in_sizes, int n_in,
                              void* d_out, int out_size, void* d_ws, size_t ws_size,
                              hipStream_t stream) {
    const float* im = (const float*)d_in[0];
    const float* R = (const float*)d_in[1];
    const float* L = (const float*)d_in[2];
    float* out = (float*)d_out;
    uint32_t* ctl = (uint32_t*)d_ws;

    int occ = 0;
    hipError_t e = hipOccupancyMaxActiveBlocksPerMultiprocessor(&occ, mega_k, 256, 0);
    if (e != hipSuccess || occ <= 0) occ = 4;
    if (occ > 8) occ = 8;
    int grid = occ * 256;  // 256 CUs on MI355X; grid must be co-resident for coop launch

    void* args[] = {(void*)&im, (void*)&R, (void*)&L, (void*)&ctl, (void*)&out};
    hipLaunchCooperativeKernel(mega_k, dim3(grid), dim3(256), args, 0, stream);
}

// Round 5
// 276.330 us; speedup vs baseline: 1.7234x; 1.7234x over previous
//
#include <hip/hip_runtime.h>
#include <stdint.h>

#define HH 2048
#define WW 2048
#define HW (HH * WW)
#define N4 (HW / 4)
#define FB 512    // fine histogram bins over fixed [0,1)
#define G1 1024   // hist blocks
#define G3 1024   // main blocks ( = (WW/4)*(HH/4)/256 )

// ws uint32 layout — total 519 words = 2076 B (PROVEN-SAFE budget; round 4's 17.4 KB faulted):
// [0..511]   fine hist
// [512..517] acc floats: 0=recon_low 1=recon_eq 2=sum|dRg| 3=sumRg 4=sum|dL|e^-10|dRg| 5=sum L*e^-10Rg
// [518]      done counter

__device__ __forceinline__ float gray_pil(float r, float g, float b) {
    float qr = floorf(fminf(fmaxf(r, 0.f), 1.f) * 255.f);
    float qg = floorf(fminf(fmaxf(g, 0.f), 1.f) * 255.f);
    float qb = floorf(fminf(fmaxf(b, 0.f), 1.f) * 255.f);
    // all terms integers < 2^24: exact in fp32
    float s = floorf((qr * 19595.f + qg * 38470.f + qb * 7471.f + 32768.f) * (1.f / 65536.f));
    return s * (1.f / 255.f);
}

// ---------------- K1: fixed-range fine histogram of per-pixel channel max ----------------
__global__ __launch_bounds__(256) void hist_k(const float* __restrict__ im, uint32_t* __restrict__ ctl) {
    __shared__ uint32_t lh[FB];
    int t = threadIdx.x;
    lh[t] = 0u;
    lh[t + 256] = 0u;
    __syncthreads();

    const float4* im4 = (const float4*)im;
    int tid = blockIdx.x * 256 + t;
#pragma unroll 2
    for (int i = tid; i < N4; i += G1 * 256) {
        float4 a = im4[i], b = im4[i + N4], c = im4[i + 2 * N4];
        float m[4];
        m[0] = fmaxf(a.x, fmaxf(b.x, c.x));
        m[1] = fmaxf(a.y, fmaxf(b.y, c.y));
        m[2] = fmaxf(a.z, fmaxf(b.z, c.z));
        m[3] = fmaxf(a.w, fmaxf(b.w, c.w));
#pragma unroll
        for (int j = 0; j < 4; ++j) {
            int bin = (int)(m[j] * (float)FB);
            bin = bin < 0 ? 0 : (bin > FB - 1 ? FB - 1 : bin);
            atomicAdd(&lh[bin], 1u);
        }
    }
    __syncthreads();
    if (lh[t]) atomicAdd(&ctl[t], lh[t]);
    if (lh[t + 256]) atomicAdd(&ctl[t + 256], lh[t + 256]);
}

// ---------------- K2: cdf derivation + fused main pass + finalize ----------------
struct Row { float4 r0, r1, r2, i0, i1, i2, lv; };

__device__ __forceinline__ Row load_row(const float* __restrict__ im,
                                        const float* __restrict__ R,
                                        const float* __restrict__ L, int p) {
    Row q;
    q.r0 = *(const float4*)(R + p);
    q.r1 = *(const float4*)(R + p + HW);
    q.r2 = *(const float4*)(R + p + 2 * HW);
    q.i0 = *(const float4*)(im + p);
    q.i1 = *(const float4*)(im + p + HW);
    q.i2 = *(const float4*)(im + p + 2 * HW);
    q.lv = *(const float4*)(L + p);
    return q;
}

__device__ __forceinline__ void px(float r0, float r1, float r2,
                                   float i0, float i1, float i2, float l,
                                   float& rgp, float& lp,
                                   const float* __restrict__ scdf, float gmin, float inv_dw,
                                   float& a0, float& a1, float& a2,
                                   float& a3, float& a4, float& a5) {
    a0 += fabsf(r0 * l - i0) + fabsf(r1 * l - i1) + fabsf(r2 * l - i2);
    float rmax = fmaxf(r0, fmaxf(r1, r2));
    float imax = fmaxf(i0, fmaxf(i1, i2));
    float t = (imax - gmin) * inv_dw;
    t = fmaxf(t, 0.f);
    int bi = (int)t;
    float eq;
    if (bi >= 255) eq = scdf[255];
    else {
        float fr = t - (float)bi;
        eq = scdf[bi] + fr * (scdf[bi + 1] - scdf[bi]);
    }
    a1 += fabsf(rmax - eq);
    float rg = gray_pil(r0, r1, r2);
    a3 += rg;
    a5 += l * __expf(-10.f * rg);
    float drg = fabsf(rg - rgp);
    a2 += drg;
    a4 += fabsf(l - lp) * __expf(-10.f * drg);
    rgp = rg;
    lp = l;
}

__device__ __forceinline__ void row_math(const Row& q, float rgp[4], float lp[4],
                                         const float* __restrict__ scdf, float gmin, float inv_dw,
                                         float& a0, float& a1, float& a2,
                                         float& a3, float& a4, float& a5) {
    px(q.r0.x, q.r1.x, q.r2.x, q.i0.x, q.i1.x, q.i2.x, q.lv.x, rgp[0], lp[0], scdf, gmin, inv_dw, a0, a1, a2, a3, a4, a5);
    px(q.r0.y, q.r1.y, q.r2.y, q.i0.y, q.i1.y, q.i2.y, q.lv.y, rgp[1], lp[1], scdf, gmin, inv_dw, a0, a1, a2, a3, a4, a5);
    px(q.r0.z, q.r1.z, q.r2.z, q.i0.z, q.i1.z, q.i2.z, q.lv.z, rgp[2], lp[2], scdf, gmin, inv_dw, a0, a1, a2, a3, a4, a5);
    px(q.r0.w, q.r1.w, q.r2.w, q.i0.w, q.i1.w, q.i2.w, q.lv.w, rgp[3], lp[3], scdf, gmin, inv_dw, a0, a1, a2, a3, a4, a5);
}

__global__ __launch_bounds__(256, 4)
void main_k(const float* __restrict__ im, const float* __restrict__ R,
            const float* __restrict__ L, uint32_t* __restrict__ ctl,
            float* __restrict__ out) {
    __shared__ uint32_t sf[FB];
    __shared__ uint32_t sc[256];
    __shared__ float scdf[256];
    __shared__ float red[6][4];
    __shared__ uint32_t smm[2];
    int t = threadIdx.x;

    // load fine hist; find first/last nonempty bin -> gmin/gmax; fold 512 -> 256 bins
    sf[t] = ctl[t];
    sf[t + 256] = ctl[t + 256];
    sc[t] = 0u;
    if (t == 0) { smm[0] = FB; smm[1] = 0u; }
    __syncthreads();
    if (sf[t]) { atomicMin(&smm[0], (uint32_t)t); atomicMax(&smm[1], (uint32_t)t); }
    if (sf[t + 256]) { atomicMin(&smm[0], (uint32_t)(t + 256)); atomicMax(&smm[1], (uint32_t)(t + 256)); }
    __syncthreads();
    float gmin = (float)smm[0] * (1.0f / (float)FB);         // left edge of first nonempty
    float gmax = (float)(smm[1] + 1u) * (1.0f / (float)FB);  // right edge of last nonempty
    float inv_dw = 256.0f / (gmax - gmin);
#pragma unroll
    for (int jj = 0; jj < 2; ++jj) {
        int j = t + jj * 256;
        uint32_t cnt = sf[j];
        if (cnt) {
            float c = ((float)j + 0.5f) * (1.0f / (float)FB);  // fine-bin center
            int q = (int)((c - gmin) * inv_dw);
            q = q < 0 ? 0 : (q > 255 ? 255 : q);
            atomicAdd(&sc[q], cnt);
        }
    }
    __syncthreads();
    // inclusive integer scan -> cdf
#pragma unroll
    for (int d = 1; d < 256; d <<= 1) {
        uint32_t v = (t >= d) ? sc[t - d] : 0u;
        __syncthreads();
        sc[t] += v;
        __syncthreads();
    }
    scdf[t] = (float)((double)sc[t] * (1.0 / (double)HW));
    __syncthreads();

    // ---- main fused pass: 4 cols x 4 rows per thread, software-pipelined loads ----
    int tid = blockIdx.x * 256 + t;
    int w = (tid & 511) * 4;
    int h0 = (tid >> 9) * 4;   // uniform per block (tid>>9 constant within a block's range? no — but divergence-free enough; all threads active)

    float a0 = 0.f, a1 = 0.f, a2 = 0.f, a3 = 0.f, a4 = 0.f, a5 = 0.f;
    float rgp[4], lp[4];
    if (h0 > 0) {
        int p = (h0 - 1) * WW + w;
        float4 Ra = *(const float4*)(R + p);
        float4 Rb = *(const float4*)(R + p + HW);
        float4 Rc = *(const float4*)(R + p + 2 * HW);
        float4 Lv = *(const float4*)(L + p);
        rgp[0] = gray_pil(Ra.x, Rb.x, Rc.x); lp[0] = Lv.x;
        rgp[1] = gray_pil(Ra.y, Rb.y, Rc.y); lp[1] = Lv.y;
        rgp[2] = gray_pil(Ra.z, Rb.z, Rc.z); lp[2] = Lv.z;
        rgp[3] = gray_pil(Ra.w, Rb.w, Rc.w); lp[3] = Lv.w;
    } else {
        rgp[0] = rgp[1] = rgp[2] = rgp[3] = 0.f;
        lp[0] = lp[1] = lp[2] = lp[3] = 0.f;
    }

    Row cur = load_row(im, R, L, h0 * WW + w);
#pragma unroll
    for (int h = 0; h < 4; ++h) {
        Row nxt;
        if (h < 3) nxt = load_row(im, R, L, (h0 + h + 1) * WW + w);
        row_math(cur, rgp, lp, scdf, gmin, inv_dw, a0, a1, a2, a3, a4, a5);
        if (h < 3) cur = nxt;
    }
    if (h0 + 4 == HH) {  // boundary at h = 2048: |0 - x[2047]|
#pragma unroll
        for (int j = 0; j < 4; ++j) {
            a2 += rgp[j];
            a4 += lp[j] * __expf(-10.f * rgp[j]);
        }
    }

    for (int off = 32; off; off >>= 1) {
        a0 += __shfl_down(a0, off);
        a1 += __shfl_down(a1, off);
        a2 += __shfl_down(a2, off);
        a3 += __shfl_down(a3, off);
        a4 += __shfl_down(a4, off);
        a5 += __shfl_down(a5, off);
    }
    int lane = t & 63, wv = t >> 6;
    if (lane == 0) {
        red[0][wv] = a0; red[1][wv] = a1; red[2][wv] = a2;
        red[3][wv] = a3; red[4][wv] = a4; red[5][wv] = a5;
    }
    __syncthreads();
    if (t == 0) {
        float s0 = 0, s1 = 0, s2 = 0, s3 = 0, s4 = 0, s5 = 0;
        for (int k = 0; k < 4; k++) {
            s0 += red[0][k]; s1 += red[1][k]; s2 += red[2][k];
            s3 += red[3][k]; s4 += red[4][k]; s5 += red[5][k];
        }
        float* acc = (float*)(ctl + 512);
        atomicAdd(&acc[0], s0);
        atomicAdd(&acc[1], s1);
        atomicAdd(&acc[2], s2);
        atomicAdd(&acc[3], s3);
        atomicAdd(&acc[4], s4);
        atomicAdd(&acc[5], s5);
        __threadfence();
        uint32_t old = atomicAdd(&ctl[518], 1u);
        if (old == G3 - 1) {  // last block: all acc atomics happened-before
            float v0 = atomicAdd(&acc[0], 0.f);
            float v1 = atomicAdd(&acc[1], 0.f);
            float v2 = atomicAdd(&acc[2], 0.f);
            float v3 = atomicAdd(&acc[3], 0.f);
            float v4 = atomicAdd(&acc[4], 0.f);
            float v5 = atomicAdd(&acc[5], 0.f);
            float recon_low = v0 / (3.0f * (float)HW);
            float recon_eq = v1 / (float)HW;
            float denom = 2.0f * 2049.0f * 2050.0f;
            float r_smooth = (v2 + 2.f * v3) / denom;
            float ismooth = (v4 + 2.f * v5) / denom;
            out[0] = recon_low + 0.1f * ismooth + 0.1f * recon_eq + 0.01f * r_smooth;
        }
    }
}

extern "C" void kernel_launch(void* const* d_in, const int* in_sizes, int n_in,
                              void* d_out, int out_size, void* d_ws, size_t ws_size,
                              hipStream_t stream) {
    const float* im = (const float*)d_in[0];
    const float* R = (const float*)d_in[1];
    const float* L = (const float*)d_in[2];
    float* out = (float*)d_out;
    uint32_t* ctl = (uint32_t*)d_ws;

    hipMemsetAsync(d_ws, 0, 520 * 4, stream);  // graph-capturable memset node
    hipLaunchKernelGGL(hist_k, dim3(G1), dim3(256), 0, stream, im, ctl);
    hipLaunchKernelGGL(main_k, dim3(G3), dim3(256), 0, stream, im, R, L, ctl, out);
}

// Round 6
// 266.072 us; speedup vs baseline: 1.7898x; 1.0386x over previous
//
#include <hip/hip_runtime.h>
#include <stdint.h>

#define HH 2048
#define WW 2048
#define HW (HH * WW)
#define N4 (HW / 4)
#define FB 512    // fine histogram bins over fixed [0,1)
#define G1 2048   // hist blocks
#define G3 1024   // main blocks ( = (WW/4)*(HH/4)/256 )

// ws uint32 layout — total 519 words = 2076 B (PROVEN-SAFE budget; 17.4 KB faulted in round 4):
// [0..511]   fine hist
// [512..517] acc floats: 0=recon_low 1=recon_eq 2=sum|dRg| 3=sumRg 4=sum|dL|e^-10|dRg| 5=sum L*e^-10Rg
// [518]      done counter

__device__ __forceinline__ float gray_pil(float r, float g, float b) {
    float qr = floorf(fminf(fmaxf(r, 0.f), 1.f) * 255.f);
    float qg = floorf(fminf(fmaxf(g, 0.f), 1.f) * 255.f);
    float qb = floorf(fminf(fmaxf(b, 0.f), 1.f) * 255.f);
    // all terms integers < 2^24: exact in fp32
    float s = floorf((qr * 19595.f + qg * 38470.f + qb * 7471.f + 32768.f) * (1.f / 65536.f));
    return s * (1.f / 255.f);
}

// ---------------- K1: fixed-range fine histogram of per-pixel channel max ----------------
__global__ __launch_bounds__(256) void hist_k(const float* __restrict__ im, uint32_t* __restrict__ ctl) {
    __shared__ uint32_t lh[FB];
    int t = threadIdx.x;
    lh[t] = 0u;
    lh[t + 256] = 0u;
    __syncthreads();

    const float4* im4 = (const float4*)im;
    int tid = blockIdx.x * 256 + t;
    for (int i = tid; i < N4; i += G1 * 256) {
        float4 a = im4[i], b = im4[i + N4], c = im4[i + 2 * N4];
        float m[4];
        m[0] = fmaxf(a.x, fmaxf(b.x, c.x));
        m[1] = fmaxf(a.y, fmaxf(b.y, c.y));
        m[2] = fmaxf(a.z, fmaxf(b.z, c.z));
        m[3] = fmaxf(a.w, fmaxf(b.w, c.w));
#pragma unroll
        for (int j = 0; j < 4; ++j) {
            int bin = (int)(m[j] * (float)FB);
            bin = bin < 0 ? 0 : (bin > FB - 1 ? FB - 1 : bin);
            atomicAdd(&lh[bin], 1u);
        }
    }
    __syncthreads();
    if (lh[t]) atomicAdd(&ctl[t], lh[t]);
    if (lh[t + 256]) atomicAdd(&ctl[t + 256], lh[t + 256]);
}

// ---------------- K2: cdf derivation + fused main pass + finalize ----------------
__device__ __forceinline__ void px(float r0, float r1, float r2,
                                   float i0, float i1, float i2, float l,
                                   float& rgp, float& lp,
                                   const float* __restrict__ scdf, float gmin, float inv_dw,
                                   float& a0, float& a1, float& a2,
                                   float& a3, float& a4, float& a5) {
    a0 += fabsf(r0 * l - i0) + fabsf(r1 * l - i1) + fabsf(r2 * l - i2);
    float rmax = fmaxf(r0, fmaxf(r1, r2));
    float imax = fmaxf(i0, fmaxf(i1, i2));
    float t = (imax - gmin) * inv_dw;
    t = fmaxf(t, 0.f);
    int bi = (int)t;
    float eq;
    if (bi >= 255) eq = scdf[255];
    else {
        float fr = t - (float)bi;
        eq = scdf[bi] + fr * (scdf[bi + 1] - scdf[bi]);
    }
    a1 += fabsf(rmax - eq);
    float rg = gray_pil(r0, r1, r2);
    a3 += rg;
    a5 += l * __expf(-10.f * rg);
    float drg = fabsf(rg - rgp);
    a2 += drg;
    a4 += fabsf(l - lp) * __expf(-10.f * drg);
    rgp = rg;
    lp = l;
}

__global__ __launch_bounds__(256)
void main_k(const float* __restrict__ im, const float* __restrict__ R,
            const float* __restrict__ L, uint32_t* __restrict__ ctl,
            float* __restrict__ out) {
    __shared__ uint32_t sf[FB];
    __shared__ uint32_t sc[256];
    __shared__ float scdf[256];
    __shared__ float red[6][4];
    __shared__ uint32_t smm[2];
    int t = threadIdx.x;

    // load fine hist; first/last nonempty bin -> gmin/gmax; fold 512 -> 256 bins
    sf[t] = ctl[t];
    sf[t + 256] = ctl[t + 256];
    sc[t] = 0u;
    if (t == 0) { smm[0] = FB; smm[1] = 0u; }
    __syncthreads();
    if (sf[t]) { atomicMin(&smm[0], (uint32_t)t); atomicMax(&smm[1], (uint32_t)t); }
    if (sf[t + 256]) { atomicMin(&smm[0], (uint32_t)(t + 256)); atomicMax(&smm[1], (uint32_t)(t + 256)); }
    __syncthreads();
    float gmin = (float)smm[0] * (1.0f / (float)FB);         // left edge of first nonempty
    float gmax = (float)(smm[1] + 1u) * (1.0f / (float)FB);  // right edge of last nonempty
    float inv_dw = 256.0f / (gmax - gmin);
#pragma unroll
    for (int jj = 0; jj < 2; ++jj) {
        int j = t + jj * 256;
        uint32_t cnt = sf[j];
        if (cnt) {
            float c = ((float)j + 0.5f) * (1.0f / (float)FB);  // fine-bin center
            int q = (int)((c - gmin) * inv_dw);
            q = q < 0 ? 0 : (q > 255 ? 255 : q);
            atomicAdd(&sc[q], cnt);
        }
    }
    __syncthreads();
    // inclusive integer scan -> cdf
#pragma unroll
    for (int d = 1; d < 256; d <<= 1) {
        uint32_t v = (t >= d) ? sc[t - d] : 0u;
        __syncthreads();
        sc[t] += v;
        __syncthreads();
    }
    scdf[t] = (float)((double)sc[t] * (1.0 / (double)HW));
    __syncthreads();

    // ---- main fused pass: 4 cols x 4 rows per thread; per-row loads, TLP hides latency ----
    int tid = blockIdx.x * 256 + t;
    int w = (tid & 511) * 4;
    int h0 = (tid >> 9) * 4;

    float a0 = 0.f, a1 = 0.f, a2 = 0.f, a3 = 0.f, a4 = 0.f, a5 = 0.f;
    float rgp[4], lp[4];
    if (h0 > 0) {
        int p = (h0 - 1) * WW + w;
        float4 Ra = *(const float4*)(R + p);
        float4 Rb = *(const float4*)(R + p + HW);
        float4 Rc = *(const float4*)(R + p + 2 * HW);
        float4 Lv = *(const float4*)(L + p);
        rgp[0] = gray_pil(Ra.x, Rb.x, Rc.x); lp[0] = Lv.x;
        rgp[1] = gray_pil(Ra.y, Rb.y, Rc.y); lp[1] = Lv.y;
        rgp[2] = gray_pil(Ra.z, Rb.z, Rc.z); lp[2] = Lv.z;
        rgp[3] = gray_pil(Ra.w, Rb.w, Rc.w); lp[3] = Lv.w;
    } else {
        rgp[0] = rgp[1] = rgp[2] = rgp[3] = 0.f;
        lp[0] = lp[1] = lp[2] = lp[3] = 0.f;
    }

#pragma unroll
    for (int h = 0; h < 4; ++h) {
        int p = (h0 + h) * WW + w;
        float4 r0 = *(const float4*)(R + p);
        float4 r1 = *(const float4*)(R + p + HW);
        float4 r2 = *(const float4*)(R + p + 2 * HW);
        float4 i0 = *(const float4*)(im + p);
        float4 i1 = *(const float4*)(im + p + HW);
        float4 i2 = *(const float4*)(im + p + 2 * HW);
        float4 lv = *(const float4*)(L + p);
        px(r0.x, r1.x, r2.x, i0.x, i1.x, i2.x, lv.x, rgp[0], lp[0], scdf, gmin, inv_dw, a0, a1, a2, a3, a4, a5);
        px(r0.y, r1.y, r2.y, i0.y, i1.y, i2.y, lv.y, rgp[1], lp[1], scdf, gmin, inv_dw, a0, a1, a2, a3, a4, a5);
        px(r0.z, r1.z, r2.z, i0.z, i1.z, i2.z, lv.z, rgp[2], lp[2], scdf, gmin, inv_dw, a0, a1, a2, a3, a4, a5);
        px(r0.w, r1.w, r2.w, i0.w, i1.w, i2.w, lv.w, rgp[3], lp[3], scdf, gmin, inv_dw, a0, a1, a2, a3, a4, a5);
    }
    if (h0 + 4 == HH) {  // boundary at h = 2048: |0 - x[2047]|
#pragma unroll
        for (int j = 0; j < 4; ++j) {
            a2 += rgp[j];
            a4 += lp[j] * __expf(-10.f * rgp[j]);
        }
    }

    for (int off = 32; off; off >>= 1) {
        a0 += __shfl_down(a0, off);
        a1 += __shfl_down(a1, off);
        a2 += __shfl_down(a2, off);
        a3 += __shfl_down(a3, off);
        a4 += __shfl_down(a4, off);
        a5 += __shfl_down(a5, off);
    }
    int lane = t & 63, wv = t >> 6;
    if (lane == 0) {
        red[0][wv] = a0; red[1][wv] = a1; red[2][wv] = a2;
        red[3][wv] = a3; red[4][wv] = a4; red[5][wv] = a5;
    }
    __syncthreads();
    if (t == 0) {
        float s0 = 0, s1 = 0, s2 = 0, s3 = 0, s4 = 0, s5 = 0;
        for (int k = 0; k < 4; k++) {
            s0 += red[0][k]; s1 += red[1][k]; s2 += red[2][k];
            s3 += red[3][k]; s4 += red[4][k]; s5 += red[5][k];
        }
        float* acc = (float*)(ctl + 512);
        atomicAdd(&acc[0], s0);
        atomicAdd(&acc[1], s1);
        atomicAdd(&acc[2], s2);
        atomicAdd(&acc[3], s3);
        atomicAdd(&acc[4], s4);
        atomicAdd(&acc[5], s5);
        __threadfence();
        uint32_t old = atomicAdd(&ctl[518], 1u);
        if (old == G3 - 1) {  // last block: all acc atomics happened-before
            float v0 = atomicAdd(&acc[0], 0.f);
            float v1 = atomicAdd(&acc[1], 0.f);
            float v2 = atomicAdd(&acc[2], 0.f);
            float v3 = atomicAdd(&acc[3], 0.f);
            float v4 = atomicAdd(&acc[4], 0.f);
            float v5 = atomicAdd(&acc[5], 0.f);
            float recon_low = v0 / (3.0f * (float)HW);
            float recon_eq = v1 / (float)HW;
            float denom = 2.0f * 2049.0f * 2050.0f;
            float r_smooth = (v2 + 2.f * v3) / denom;
            float ismooth = (v4 + 2.f * v5) / denom;
            out[0] = recon_low + 0.1f * ismooth + 0.1f * recon_eq + 0.01f * r_smooth;
        }
    }
}

extern "C" void kernel_launch(void* const* d_in, const int* in_sizes, int n_in,
                              void* d_out, int out_size, void* d_ws, size_t ws_size,
                              hipStream_t stream) {
    const float* im = (const float*)d_in[0];
    const float* R = (const float*)d_in[1];
    const float* L = (const float*)d_in[2];
    float* out = (float*)d_out;
    uint32_t* ctl = (uint32_t*)d_ws;

    hipMemsetAsync(d_ws, 0, 520 * 4, stream);  // graph-capturable memset node
    hipLaunchKernelGGL(hist_k, dim3(G1), dim3(256), 0, stream, im, ctl);
    hipLaunchKernelGGL(main_k, dim3(G3), dim3(256), 0, stream, im, R, L, ctl, out);
}

// Round 7
// 204.935 us; speedup vs baseline: 2.3238x; 1.2983x over previous
//
#include <hip/hip_runtime.h>
#include <stdint.h>

#define HH 2048
#define WW 2048
#define HW (HH * WW)
#define N4 (HW / 4)
#define FB 512    // fine histogram bins over fixed [0,1)
#define G1 512    // hist blocks  -> 8 iters/thread
#define G3 512    // main blocks: dim3(2, 256), 8 rows/thread

// ws uint32 layout — 519 words = 2076 B (PROVEN-SAFE; 17.4 KB faulted in round 4):
// [0..511]   fine hist; AFTER cdf_k: [0..255] = cdf (float), [256]=gmin (float), [257]=gmax (float)
// [512..517] acc floats: 0=recon_low 1=recon_eq 2=sum|dRg| 3=sumRg 4=sum|dL|e^-10|dRg| 5=sum L*e^-10Rg
// [518]      done counter

__device__ __forceinline__ float gray_pil(float r, float g, float b) {
    float qr = floorf(fminf(fmaxf(r, 0.f), 1.f) * 255.f);
    float qg = floorf(fminf(fmaxf(g, 0.f), 1.f) * 255.f);
    float qb = floorf(fminf(fmaxf(b, 0.f), 1.f) * 255.f);
    // all terms integers < 2^24: exact in fp32
    float s = floorf((qr * 19595.f + qg * 38470.f + qb * 7471.f + 32768.f) * (1.f / 65536.f));
    return s * (1.f / 255.f);
}

// ---------------- K1: fixed-range fine histogram of per-pixel channel max ----------------
__global__ __launch_bounds__(256) void hist_k(const float* __restrict__ im, uint32_t* __restrict__ ctl) {
    __shared__ uint32_t lh[FB];
    int t = threadIdx.x;
    lh[t] = 0u;
    lh[t + 256] = 0u;
    __syncthreads();

    const float4* im4 = (const float4*)im;
    int tid = blockIdx.x * 256 + t;
    for (int i = tid; i < N4; i += G1 * 256) {   // 8 iterations: deep steady-state streaming
        float4 a = im4[i], b = im4[i + N4], c = im4[i + 2 * N4];
        float m[4];
        m[0] = fmaxf(a.x, fmaxf(b.x, c.x));
        m[1] = fmaxf(a.y, fmaxf(b.y, c.y));
        m[2] = fmaxf(a.z, fmaxf(b.z, c.z));
        m[3] = fmaxf(a.w, fmaxf(b.w, c.w));
#pragma unroll
        for (int j = 0; j < 4; ++j) {
            int bin = (int)(m[j] * (float)FB);
            bin = bin < 0 ? 0 : (bin > FB - 1 ? FB - 1 : bin);
            atomicAdd(&lh[bin], 1u);
        }
    }
    __syncthreads();
    if (lh[t]) atomicAdd(&ctl[t], lh[t]);
    if (lh[t + 256]) atomicAdd(&ctl[t + 256], lh[t + 256]);
}

// ---------------- K2: tiny single-block cdf derivation ----------------
__global__ __launch_bounds__(256) void cdf_k(uint32_t* __restrict__ ctl) {
    __shared__ uint32_t sf[FB];
    __shared__ uint32_t sc[256];
    __shared__ uint32_t smm[2];
    int t = threadIdx.x;
    sf[t] = ctl[t];
    sf[t + 256] = ctl[t + 256];
    sc[t] = 0u;
    if (t == 0) { smm[0] = FB; smm[1] = 0u; }
    __syncthreads();
    if (sf[t]) { atomicMin(&smm[0], (uint32_t)t); atomicMax(&smm[1], (uint32_t)t); }
    if (sf[t + 256]) { atomicMin(&smm[0], (uint32_t)(t + 256)); atomicMax(&smm[1], (uint32_t)(t + 256)); }
    __syncthreads();
    float gmin = (float)smm[0] * (1.0f / (float)FB);         // left edge of first nonempty fine bin
    float gmax = (float)(smm[1] + 1u) * (1.0f / (float)FB);  // right edge of last nonempty fine bin
    float inv_dw = 256.0f / (gmax - gmin);
#pragma unroll
    for (int jj = 0; jj < 2; ++jj) {
        int j = t + jj * 256;
        uint32_t cnt = sf[j];
        if (cnt) {
            float c = ((float)j + 0.5f) * (1.0f / (float)FB);  // fine-bin center
            int q = (int)((c - gmin) * inv_dw);
            q = q < 0 ? 0 : (q > 255 ? 255 : q);
            atomicAdd(&sc[q], cnt);
        }
    }
    __syncthreads();
    // inclusive integer scan -> cdf
#pragma unroll
    for (int d = 1; d < 256; d <<= 1) {
        uint32_t v = (t >= d) ? sc[t - d] : 0u;
        __syncthreads();
        sc[t] += v;
        __syncthreads();
    }
    float* cf = (float*)ctl;
    cf[t] = (float)((double)sc[t] * (1.0 / (double)HW));  // overwrite hist[0..255] with cdf
    if (t == 0) { cf[256] = gmin; cf[257] = gmax; }
}

// ---------------- K3: fused main pass (round-2 structure) + finalize ----------------
__device__ __forceinline__ void px(float r0, float r1, float r2,
                                   float i0, float i1, float i2, float l,
                                   float& rgp, float& lp,
                                   const float* __restrict__ scdf, float gmin, float inv_dw,
                                   float& a0, float& a1, float& a2,
                                   float& a3, float& a4, float& a5) {
    a0 += fabsf(r0 * l - i0) + fabsf(r1 * l - i1) + fabsf(r2 * l - i2);
    float rmax = fmaxf(r0, fmaxf(r1, r2));
    float imax = fmaxf(i0, fmaxf(i1, i2));
    float t = (imax - gmin) * inv_dw;
    t = fmaxf(t, 0.f);
    int bi = (int)t;
    float eq;
    if (bi >= 255) eq = scdf[255];
    else {
        float fr = t - (float)bi;
        eq = scdf[bi] + fr * (scdf[bi + 1] - scdf[bi]);
    }
    a1 += fabsf(rmax - eq);
    float rg = gray_pil(r0, r1, r2);
    a3 += rg;
    a5 += l * __expf(-10.f * rg);
    float drg = fabsf(rg - rgp);
    a2 += drg;
    a4 += fabsf(l - lp) * __expf(-10.f * drg);
    rgp = rg;
    lp = l;
}

__global__ __launch_bounds__(256)
void main_k(const float* __restrict__ im, const float* __restrict__ R,
            const float* __restrict__ L, uint32_t* __restrict__ ctl,
            float* __restrict__ out) {
    __shared__ float scdf[256];
    __shared__ float red[6][4];
    int t = threadIdx.x;

    scdf[t] = ((const float*)ctl)[t];
    float gmin = ((const float*)ctl)[256];
    float gmax = ((const float*)ctl)[257];
    float inv_dw = 256.0f / (gmax - gmin);
    __syncthreads();

    int w = (blockIdx.x * 256 + t) * 4;  // 4 adjacent columns per thread
    int h0 = blockIdx.y * 8;             // 8-row tile

    float a0 = 0.f, a1 = 0.f, a2 = 0.f, a3 = 0.f, a4 = 0.f, a5 = 0.f;
    float rgp[4], lp[4];
    if (h0 > 0) {
        int p = (h0 - 1) * WW + w;
        float4 Ra = *(const float4*)(R + p);
        float4 Rb = *(const float4*)(R + p + HW);
        float4 Rc = *(const float4*)(R + p + 2 * HW);
        float4 Lv = *(const float4*)(L + p);
        rgp[0] = gray_pil(Ra.x, Rb.x, Rc.x); lp[0] = Lv.x;
        rgp[1] = gray_pil(Ra.y, Rb.y, Rc.y); lp[1] = Lv.y;
        rgp[2] = gray_pil(Ra.z, Rb.z, Rc.z); lp[2] = Lv.z;
        rgp[3] = gray_pil(Ra.w, Rb.w, Rc.w); lp[3] = Lv.w;
    } else {
        rgp[0] = rgp[1] = rgp[2] = rgp[3] = 0.f;
        lp[0] = lp[1] = lp[2] = lp[3] = 0.f;
    }

#pragma unroll 2
    for (int h = h0; h < h0 + 8; ++h) {
        int p = h * WW + w;
        float4 r0 = *(const float4*)(R + p);
        float4 r1 = *(const float4*)(R + p + HW);
        float4 r2 = *(const float4*)(R + p + 2 * HW);
        float4 i0 = *(const float4*)(im + p);
        float4 i1 = *(const float4*)(im + p + HW);
        float4 i2 = *(const float4*)(im + p + 2 * HW);
        float4 lv = *(const float4*)(L + p);
        px(r0.x, r1.x, r2.x, i0.x, i1.x, i2.x, lv.x, rgp[0], lp[0], scdf, gmin, inv_dw, a0, a1, a2, a3, a4, a5);
        px(r0.y, r1.y, r2.y, i0.y, i1.y, i2.y, lv.y, rgp[1], lp[1], scdf, gmin, inv_dw, a0, a1, a2, a3, a4, a5);
        px(r0.z, r1.z, r2.z, i0.z, i1.z, i2.z, lv.z, rgp[2], lp[2], scdf, gmin, inv_dw, a0, a1, a2, a3, a4, a5);
        px(r0.w, r1.w, r2.w, i0.w, i1.w, i2.w, lv.w, rgp[3], lp[3], scdf, gmin, inv_dw, a0, a1, a2, a3, a4, a5);
    }
    if (h0 + 8 == HH) {  // boundary at h = 2048: |0 - x[2047]|
#pragma unroll
        for (int j = 0; j < 4; ++j) {
            a2 += rgp[j];
            a4 += lp[j] * __expf(-10.f * rgp[j]);
        }
    }

    for (int off = 32; off; off >>= 1) {
        a0 += __shfl_down(a0, off);
        a1 += __shfl_down(a1, off);
        a2 += __shfl_down(a2, off);
        a3 += __shfl_down(a3, off);
        a4 += __shfl_down(a4, off);
        a5 += __shfl_down(a5, off);
    }
    int lane = t & 63, wv = t >> 6;
    if (lane == 0) {
        red[0][wv] = a0; red[1][wv] = a1; red[2][wv] = a2;
        red[3][wv] = a3; red[4][wv] = a4; red[5][wv] = a5;
    }
    __syncthreads();
    if (t == 0) {
        float s0 = 0, s1 = 0, s2 = 0, s3 = 0, s4 = 0, s5 = 0;
        for (int k = 0; k < 4; k++) {
            s0 += red[0][k]; s1 += red[1][k]; s2 += red[2][k];
            s3 += red[3][k]; s4 += red[4][k]; s5 += red[5][k];
        }
        float* acc = (float*)(ctl + 512);
        atomicAdd(&acc[0], s0);
        atomicAdd(&acc[1], s1);
        atomicAdd(&acc[2], s2);
        atomicAdd(&acc[3], s3);
        atomicAdd(&acc[4], s4);
        atomicAdd(&acc[5], s5);
        __threadfence();
        uint32_t old = atomicAdd(&ctl[518], 1u);
        if (old == G3 - 1) {  // last block: all acc atomics happened-before
            float v0 = atomicAdd(&acc[0], 0.f);
            float v1 = atomicAdd(&acc[1], 0.f);
            float v2 = atomicAdd(&acc[2], 0.f);
            float v3 = atomicAdd(&acc[3], 0.f);
            float v4 = atomicAdd(&acc[4], 0.f);
            float v5 = atomicAdd(&acc[5], 0.f);
            float recon_low = v0 / (3.0f * (float)HW);
            float recon_eq = v1 / (float)HW;
            float denom = 2.0f * 2049.0f * 2050.0f;
            float r_smooth = (v2 + 2.f * v3) / denom;
            float ismooth = (v4 + 2.f * v5) / denom;
            out[0] = recon_low + 0.1f * ismooth + 0.1f * recon_eq + 0.01f * r_smooth;
        }
    }
}

extern "C" void kernel_launch(void* const* d_in, const int* in_sizes, int n_in,
                              void* d_out, int out_size, void* d_ws, size_t ws_size,
                              hipStream_t stream) {
    const float* im = (const float*)d_in[0];
    const float* R = (const float*)d_in[1];
    const float* L = (const float*)d_in[2];
    float* out = (float*)d_out;
    uint32_t* ctl = (uint32_t*)d_ws;

    hipMemsetAsync(d_ws, 0, 519 * 4, stream);  // graph-capturable memset node
    hipLaunchKernelGGL(hist_k, dim3(G1), dim3(256), 0, stream, im, ctl);
    hipLaunchKernelGGL(cdf_k, dim3(1), dim3(256), 0, stream, ctl);
    hipLaunchKernelGGL(main_k, dim3(2, 256), dim3(256), 0, stream, im, R, L, ctl, out);
}